// Round 7
// baseline (224.460 us; speedup 1.0000x reference)
//
#include <hip/hip_runtime.h>
#include <math.h>

#define NROWS 2400
#define NCLS  91
#define L     128
#define KSUB  23
#define NKEEP 256

// d_ws float layout:
// [0, 2944)        csub_g[23][128]  (written by K1 block 0)
// [4096, 4096+2400*128*24)  M1g[br][i][24]  (29.5 MB)
#define WS_M1_OFF 4096

// K1 LDS float layout:
// [0, 2944)      Csub[23][128]
// [2944, 3968)   double tab[512]
// [3968, 4520)   coef[23][24]
#define TAB_OFF  2944
#define COEF_OFF 3968
#define K1_SMEM  4520

// ---------------------------------------------------------------------------
// K1: scores/labels/boxes + Csub build (bit-identical f64) + zigzag scatter +
//     stage-1 GEMM (M1t[v][i] = sum_u Csub[u][i]*coef[u][v]) -> global M1g.
//     Part D chains identical to R6 (ascending u per element).
// ---------------------------------------------------------------------------
__global__ void __launch_bounds__(512)
k1_stage1(const float* __restrict__ logits,
          const float* __restrict__ pboxes,
          const float* __restrict__ vecs,
          const int*   __restrict__ tsz,
          float* __restrict__ ws,
          float* __restrict__ out)
{
    __shared__ float smem[K1_SMEM];
    const int br  = blockIdx.x;
    const int tid = threadIdx.x;

    // ---------- Part A: scores / labels / boxes (wave 0 only) ----------
    if (tid < 64) {
        const float* lrow = logits + (size_t)br * NCLS;
        float p = 1.0f / (1.0f + expf(-lrow[tid]));
        int   bi = tid;
        if (tid < NCLS - 64) {
            float p2 = 1.0f / (1.0f + expf(-lrow[tid + 64]));
            if (p2 > p) { p = p2; bi = tid + 64; }    // tie -> keep lower index
        }
        #pragma unroll
        for (int off = 32; off > 0; off >>= 1) {
            float po = __shfl_xor(p, off, 64);
            int   io = __shfl_xor(bi, off, 64);
            if (po > p || (po == p && io < bi)) { p = po; bi = io; }
        }
        if (tid == 0) {
            out[br] = p;
            out[NROWS + br] = (float)bi;
            const int b = br / 300;
            const float W = (float)tsz[2 * b + 1];
            const float H = (float)tsz[2 * b + 0];
            const float4 bx = *(const float4*)(pboxes + (size_t)br * 4);
            float4 o;
            o.x = (bx.x - 0.5f * bx.z) * W;
            o.y = (bx.y - 0.5f * bx.w) * H;
            o.z = (bx.x + 0.5f * bx.z) * W;
            o.w = (bx.y + 0.5f * bx.w) * H;
            *(float4*)(out + 2 * NROWS + (size_t)br * 4) = o;
        }
    }

    // ---------- Phase 1: f64 cos table ----------
    double* tab = (double*)&smem[TAB_OFF];
    if (tid < 512) tab[tid] = cos((3.14159265358979323846 / 256.0) * (double)tid);
    __syncthreads();

    // ---------- Phase 2: Csub build (bit-identical f64 math) + coef zero/scatter ----------
    {
        const double s0 = sqrt(1.0 / 128.0);
        for (int idx = tid; idx < KSUB * L; idx += 512) {
            const int u = idx >> 7, m = idx & 127;
            float v;
            if (u == 0) v = (float)s0;
            else        v = (float)(0.125 * tab[((2 * m + 1) * u) & 511]); // sqrt(2/128)=0.125
            smem[idx] = v;
        }
    }
    float* coef = &smem[COEF_OFF];
    for (int t = tid; t < KSUB * 24; t += 512) {
        const int u = t / 24, v = t - u * 24;
        const int s = u + v;
        if (v == 23 || s > 22 || (s == 22 && u < 20)) coef[t] = 0.0f;
    }
    if (tid < NKEEP) {
        const int k = tid;
        int s = 0;
        while ((s + 1) * (s + 2) / 2 <= k) ++s;
        const int r = k - s * (s + 1) / 2;
        const int u  = (s & 1) ? r : (s - r);
        const int vv = (s & 1) ? (s - r) : r;
        coef[u * 24 + vv] = vecs[(size_t)br * NKEEP + k];
    }
    __syncthreads();

    // block 0 publishes Csub for K2 (bit-identical across blocks)
    if (br == 0) {
        for (int t = tid; t < KSUB * L; t += 512) ws[t] = smem[t];
    }

    // ---------- Part D: M1t[v][i] -> global, row-major [i][24] ----------
    {
        const int i = tid & 127;
        const int g = tid >> 7;                         // wave-uniform v-group
        float cs[KSUB];
        #pragma unroll
        for (int u = 0; u < KSUB; ++u) cs[u] = smem[u * L + i];

        float* dst = ws + WS_M1_OFF + ((size_t)br * 128 + i) * 24;
        const int vbase = g * 6;
        float a[6];
        #pragma unroll
        for (int v = 0; v < 6; ++v) a[v] = 0.0f;
        if (g < 3) {
            #pragma unroll
            for (int u = 0; u < KSUB; ++u) {
                const float2 c0 = *(const float2*)&coef[u * 24 + vbase + 0];
                const float2 c1 = *(const float2*)&coef[u * 24 + vbase + 2];
                const float2 c2 = *(const float2*)&coef[u * 24 + vbase + 4];
                const float cu = cs[u];
                a[0] += cu * c0.x; a[1] += cu * c0.y;
                a[2] += cu * c1.x; a[3] += cu * c1.y;
                a[4] += cu * c2.x; a[5] += cu * c2.y;
            }
            *(float2*)(dst + vbase + 0) = make_float2(a[0], a[1]);
            *(float2*)(dst + vbase + 2) = make_float2(a[2], a[3]);
            *(float2*)(dst + vbase + 4) = make_float2(a[4], a[5]);
        } else {
            #pragma unroll
            for (int u = 0; u < KSUB; ++u) {
                const float2 c0 = *(const float2*)&coef[u * 24 + 18];
                const float2 c1 = *(const float2*)&coef[u * 24 + 20];
                const float  c2 = coef[u * 24 + 22];
                const float cu = cs[u];
                a[0] += cu * c0.x; a[1] += cu * c0.y;
                a[2] += cu * c1.x; a[3] += cu * c1.y;
                a[4] += cu * c2;
            }
            *(float2*)(dst + 18) = make_float2(a[0], a[1]);
            *(float2*)(dst + 20) = make_float2(a[2], a[3]);
            dst[22] = a[4];
            dst[23] = 0.0f;
        }
    }
}

// ---------------------------------------------------------------------------
// K2: zero-LDS stage-2. Wave w owns rows [16w,16w+16); lane owns cols {2l,2l+1}.
// C column-pair in 46 VGPRs (loaded once); M1 row via wave-uniform loads.
// Per-element chain: ascending v, one FMA per v -> bit-identical to R6 Part E.
// ---------------------------------------------------------------------------
__global__ void __launch_bounds__(512)
k2_stage2(const float* __restrict__ ws,
          float* __restrict__ out)
{
    __shared__ float red[16];
    const int br   = blockIdx.x;
    const int tid  = threadIdx.x;
    const int lane = tid & 63;
    const int i0   = __builtin_amdgcn_readfirstlane((tid >> 6) * 16);

    // C[v][2l..2l+1] in registers, once per block (L2-hot, 11.8 KB shared)
    float2 creg[KSUB];
    {
        const float* cbase = ws + 2 * lane;
        #pragma unroll
        for (int v = 0; v < KSUB; ++v)
            creg[v] = *(const float2*)(cbase + v * L);
    }

    float acc[16][2];
    const float* mrow = ws + WS_M1_OFF + ((size_t)br * 128 + i0) * 24;

    #pragma unroll 2
    for (int r = 0; r < 16; ++r) {
        const float4* m4 = (const float4*)(mrow + r * 24);
        const float4 ma = m4[0], mb = m4[1], mc = m4[2];
        const float4 md = m4[3], me = m4[4], mf = m4[5];
        float a0 = 0.0f, a1 = 0.0f;
        a0 += ma.x * creg[0].x;  a1 += ma.x * creg[0].y;
        a0 += ma.y * creg[1].x;  a1 += ma.y * creg[1].y;
        a0 += ma.z * creg[2].x;  a1 += ma.z * creg[2].y;
        a0 += ma.w * creg[3].x;  a1 += ma.w * creg[3].y;
        a0 += mb.x * creg[4].x;  a1 += mb.x * creg[4].y;
        a0 += mb.y * creg[5].x;  a1 += mb.y * creg[5].y;
        a0 += mb.z * creg[6].x;  a1 += mb.z * creg[6].y;
        a0 += mb.w * creg[7].x;  a1 += mb.w * creg[7].y;
        a0 += mc.x * creg[8].x;  a1 += mc.x * creg[8].y;
        a0 += mc.y * creg[9].x;  a1 += mc.y * creg[9].y;
        a0 += mc.z * creg[10].x; a1 += mc.z * creg[10].y;
        a0 += mc.w * creg[11].x; a1 += mc.w * creg[11].y;
        a0 += md.x * creg[12].x; a1 += md.x * creg[12].y;
        a0 += md.y * creg[13].x; a1 += md.y * creg[13].y;
        a0 += md.z * creg[14].x; a1 += md.z * creg[14].y;
        a0 += md.w * creg[15].x; a1 += md.w * creg[15].y;
        a0 += me.x * creg[16].x; a1 += me.x * creg[16].y;
        a0 += me.y * creg[17].x; a1 += me.y * creg[17].y;
        a0 += me.z * creg[18].x; a1 += me.z * creg[18].y;
        a0 += me.w * creg[19].x; a1 += me.w * creg[19].y;
        a0 += mf.x * creg[20].x; a1 += mf.x * creg[20].y;
        a0 += mf.y * creg[21].x; a1 += mf.y * creg[21].y;
        a0 += mf.z * creg[22].x; a1 += mf.z * creg[22].y;
        acc[r][0] = a0; acc[r][1] = a1;
    }

    // ---------- min/max reduce -> threshold ----------
    float mn = acc[0][0], mx = acc[0][0];
    #pragma unroll
    for (int r = 0; r < 16; ++r) {
        mn = fminf(mn, fminf(acc[r][0], acc[r][1]));
        mx = fmaxf(mx, fmaxf(acc[r][0], acc[r][1]));
    }
    #pragma unroll
    for (int off = 32; off > 0; off >>= 1) {
        mn = fminf(mn, __shfl_xor(mn, off, 64));
        mx = fmaxf(mx, __shfl_xor(mx, off, 64));
    }
    const int w = tid >> 6;
    if (lane == 0) { red[w] = mn; red[8 + w] = mx; }
    __syncthreads();
    float gmn = red[0], gmx = red[8];
    #pragma unroll
    for (int k = 1; k < 8; ++k) {
        gmn = fminf(gmn, red[k]);
        gmx = fmaxf(gmx, red[8 + k]);
    }
    const float thr = (gmx + gmn) * 0.5f;

    // ---------- binarize + coalesced float2 stores ----------
    float* omask = out + 6 * NROWS + (size_t)br * (L * L) + 2 * lane;
    #pragma unroll
    for (int r = 0; r < 16; ++r) {
        float2 o;
        o.x = acc[r][0] > thr ? 1.0f : 0.0f;
        o.y = acc[r][1] > thr ? 1.0f : 0.0f;
        *(float2*)(omask + (size_t)(i0 + r) * L) = o;
    }
}

extern "C" void kernel_launch(void* const* d_in, const int* in_sizes, int n_in,
                              void* d_out, int out_size, void* d_ws, size_t ws_size,
                              hipStream_t stream)
{
    const float* logits = (const float*)d_in[0];
    const float* pboxes = (const float*)d_in[1];
    const float* vecs   = (const float*)d_in[2];
    const int*   tsz    = (const int*)d_in[3];
    float* out = (float*)d_out;
    float* ws  = (float*)d_ws;
    (void)in_sizes; (void)n_in; (void)out_size; (void)ws_size;

    k1_stage1<<<dim3(NROWS), dim3(512), 0, stream>>>(logits, pboxes, vecs, tsz, ws, out);
    k2_stage2<<<dim3(NROWS), dim3(512), 0, stream>>>(ws, out);
}

// Round 8
// 173.368 us; speedup vs baseline: 1.2947x; 1.2947x over previous
//
#include <hip/hip_runtime.h>
#include <math.h>

#define NROWS 2400
#define NCLS  91
#define L     128
#define KSUB  23
#define NKEEP 256
#define STR   40    // ushort row stride for frag buffers: 80B -> 16B-aligned, 2-way banks (free)

typedef short  bf16x8 __attribute__((ext_vector_type(8)));   // 8 bf16 = 4 VGPRs (per guide §3)
typedef float  f32x4  __attribute__((ext_vector_type(4)));

// LDS byte layout:
// [0,     10240)  Ctb[128][STR] ushort : Ctb[i][k] = bf16(C[k][i]); k in [23,32) zero; [32,40) unused
// [10240, 12800)  A1 [32][STR]  ushort : A1[v][u] = bf16(coef[u][v]); zero elsewhere
// [12800, 23040)  Abuf[128][STR] ushort: Abuf[i][v] = bf16(M1t[v][i])  (phase 1-2: double tab[512] overlaps)
// [23040, 23104)  red[16] float
#define CTB_OFF  0
#define A1_OFF   10240
#define ABUF_OFF 12800
#define TAB_OFF  12800
#define RED_OFF  23040
#define SMEM_BYTES 23104

__device__ __forceinline__ unsigned short f2bf(float f) {
    unsigned int u = __float_as_uint(f);
    unsigned int r = u + 0x7fffu + ((u >> 16) & 1u);   // round-to-nearest-even
    return (unsigned short)(r >> 16);
}

__global__ void __launch_bounds__(512)
postproc_kernel(const float* __restrict__ logits,
                const float* __restrict__ pboxes,
                const float* __restrict__ vecs,
                const int*   __restrict__ tsz,
                float* __restrict__ out)
{
    __shared__ __align__(16) unsigned char sm[SMEM_BYTES];
    unsigned short* Ctb = (unsigned short*)(sm + CTB_OFF);
    unsigned short* A1  = (unsigned short*)(sm + A1_OFF);
    unsigned short* Ab  = (unsigned short*)(sm + ABUF_OFF);
    double*         tab = (double*)(sm + TAB_OFF);
    float*          red = (float*)(sm + RED_OFF);

    const int br  = blockIdx.x;
    const int tid = threadIdx.x;

    // ---------- Part A: scores / labels / boxes (wave 0 only; exact fp32 path, unchanged) ----------
    if (tid < 64) {
        const float* lrow = logits + (size_t)br * NCLS;
        float p = 1.0f / (1.0f + expf(-lrow[tid]));
        int   bi = tid;
        if (tid < NCLS - 64) {
            float p2 = 1.0f / (1.0f + expf(-lrow[tid + 64]));
            if (p2 > p) { p = p2; bi = tid + 64; }    // tie -> keep lower index
        }
        #pragma unroll
        for (int off = 32; off > 0; off >>= 1) {
            float po = __shfl_xor(p, off, 64);
            int   io = __shfl_xor(bi, off, 64);
            if (po > p || (po == p && io < bi)) { p = po; bi = io; }
        }
        if (tid == 0) {
            out[br] = p;
            out[NROWS + br] = (float)bi;
            const int b = br / 300;
            const float W = (float)tsz[2 * b + 1];
            const float H = (float)tsz[2 * b + 0];
            const float4 bx = *(const float4*)(pboxes + (size_t)br * 4);
            float4 o;
            o.x = (bx.x - 0.5f * bx.z) * W;
            o.y = (bx.y - 0.5f * bx.w) * H;
            o.z = (bx.x + 0.5f * bx.z) * W;
            o.w = (bx.y + 0.5f * bx.w) * H;
            *(float4*)(out + 2 * NROWS + (size_t)br * 4) = o;
        }
    }

    // ---------- Phase 1: f64 cos table + zero A1 ----------
    tab[tid] = cos((3.14159265358979323846 / 256.0) * (double)tid);
    for (int t = tid; t < 320; t += 512)                 // 32*40 ushorts = 320 u64
        ((unsigned long long*)A1)[t] = 0ull;
    __syncthreads();

    // ---------- Phase 2: Ctb (bf16 DCT, 128 x 32) + zigzag scatter into A1 ----------
    {
        const float s0 = (float)sqrt(1.0 / 128.0);
        for (int idx = tid; idx < 128 * 32; idx += 512) {
            const int i = idx >> 5, k = idx & 31;
            float v;
            if (k == 0)       v = s0;
            else if (k < 23)  v = (float)(0.125 * tab[((2 * i + 1) * k) & 511]);
            else              v = 0.0f;
            Ctb[i * STR + k] = f2bf(v);
        }
    }
    if (tid < NKEEP) {
        const int k = tid;
        int s = 0;
        while ((s + 1) * (s + 2) / 2 <= k) ++s;          // zigzag diagonal, s <= 22
        const int r = k - s * (s + 1) / 2;
        const int u  = (s & 1) ? r : (s - r);
        const int vv = (s & 1) ? (s - r) : r;
        A1[vv * STR + u] = f2bf(vecs[(size_t)br * NKEEP + k]);
    }
    __syncthreads();                                     // tab dead from here (Abuf overlaps it)

    const int w  = tid >> 6;                             // wave id 0..7 (uniform)
    const int ml = tid & 15;
    const int kq = (tid & 63) >> 4;                      // quad 0..3

    // ---------- Stage 1 MFMA: D1[v][i] = sum_u A1[v][u] * C[u][i]  -> Abuf[i][v] (bf16) ----------
    {
        const f32x4 cz = {0.0f, 0.0f, 0.0f, 0.0f};
        #pragma unroll
        for (int p = 0; p < 2; ++p) {
            const int idx = 2 * w + p;                   // 16 tiles: tr in {0,1}, tc in 0..7
            const int tr = idx >> 3, tc = idx & 7;
            bf16x8 a1 = *(const bf16x8*)(A1  + (tr * 16 + ml) * STR + kq * 8);
            bf16x8 b1 = *(const bf16x8*)(Ctb + (tc * 16 + ml) * STR + kq * 8);
            f32x4 d1 = __builtin_amdgcn_mfma_f32_16x16x32_bf16(a1, b1, cz, 0, 0, 0);
            // lane holds D1[v = tr*16 + kq*4 + r][i = tc*16 + ml] -> transpose into Abuf[i][v]
            #pragma unroll
            for (int r = 0; r < 4; ++r)
                Ab[(tc * 16 + ml) * STR + tr * 16 + kq * 4 + r] = f2bf(d1[r]);
        }
    }
    __syncthreads();

    // ---------- Stage 2 MFMA: re[i][j] = sum_v Abuf[i][v] * C[v][j] ----------
    f32x4 acc[8];
    {
        const f32x4 cz = {0.0f, 0.0f, 0.0f, 0.0f};
        bf16x8 a2 = *(const bf16x8*)(Ab + (w * 16 + ml) * STR + kq * 8);   // wave owns row-block w
        #pragma unroll
        for (int s = 0; s < 8; ++s) {
            bf16x8 b2 = *(const bf16x8*)(Ctb + (s * 16 + ml) * STR + kq * 8);
            acc[s] = __builtin_amdgcn_mfma_f32_16x16x32_bf16(a2, b2, cz, 0, 0, 0);
        }
    }

    // ---------- min/max reduce -> threshold ----------
    float mn = acc[0][0], mx = acc[0][0];
    #pragma unroll
    for (int s = 0; s < 8; ++s)
        #pragma unroll
        for (int r = 0; r < 4; ++r) {
            mn = fminf(mn, acc[s][r]);
            mx = fmaxf(mx, acc[s][r]);
        }
    #pragma unroll
    for (int off = 32; off > 0; off >>= 1) {
        mn = fminf(mn, __shfl_xor(mn, off, 64));
        mx = fmaxf(mx, __shfl_xor(mx, off, 64));
    }
    if ((tid & 63) == 0) { red[w] = mn; red[8 + w] = mx; }
    __syncthreads();
    float gmn = red[0], gmx = red[8];
    #pragma unroll
    for (int k = 1; k < 8; ++k) {
        gmn = fminf(gmn, red[k]);
        gmx = fmaxf(gmx, red[8 + k]);
    }
    const float thr = (gmx + gmn) * 0.5f;

    // ---------- binarize + store (C-layout: row = w*16 + kq*4 + r, col = s*16 + ml) ----------
    float* omask = out + 6 * NROWS + (size_t)br * (L * L);
    #pragma unroll
    for (int s = 0; s < 8; ++s)
        #pragma unroll
        for (int r = 0; r < 4; ++r)
            omask[(size_t)(w * 16 + kq * 4 + r) * L + s * 16 + ml] =
                acc[s][r] > thr ? 1.0f : 0.0f;
}

extern "C" void kernel_launch(void* const* d_in, const int* in_sizes, int n_in,
                              void* d_out, int out_size, void* d_ws, size_t ws_size,
                              hipStream_t stream)
{
    const float* logits = (const float*)d_in[0];
    const float* pboxes = (const float*)d_in[1];
    const float* vecs   = (const float*)d_in[2];
    const int*   tsz    = (const int*)d_in[3];
    float* out = (float*)d_out;
    (void)d_ws; (void)ws_size; (void)in_sizes; (void)n_in; (void)out_size;

    postproc_kernel<<<dim3(NROWS), dim3(512), 0, stream>>>(logits, pboxes, vecs, tsz, out);
}

// Round 9
// 172.391 us; speedup vs baseline: 1.3020x; 1.0057x over previous
//
#include <hip/hip_runtime.h>
#include <math.h>

#define NROWS 2400
#define NCLS  91
#define L     128
#define KSUB  23
#define NKEEP 256
#define STR   40    // ushort row stride: 80B -> 16B-aligned, 2-way banks (free)

typedef short  bf16x8 __attribute__((ext_vector_type(8)));   // 8 bf16 = 4 VGPRs
typedef float  f32x4  __attribute__((ext_vector_type(4)));

// LDS byte layout:
// [0,     10240)  Ctb[128][STR] ushort : Ctb[i][k] = bf16(C[k][i]); k in [23,40) zero
// [10240, 12800)  A1 [32][STR]  ushort : A1[v][u] = bf16(coef[u][v]); zero elsewhere
// [12800, 23040)  Ab [128][STR] ushort : Ab[i][v] = bf16(M1t[v][i])
// [23040, 23104)  red[16] float
#define CTB_OFF  0
#define A1_OFF   10240
#define ABUF_OFF 12800
#define RED_OFF  23040
#define SMEM_BYTES 23104

__device__ __forceinline__ unsigned short f2bf(float f) {
    unsigned int u = __float_as_uint(f);
    unsigned int r = u + 0x7fffu + ((u >> 16) & 1u);   // round-to-nearest-even
    return (unsigned short)(r >> 16);
}

__global__ void __launch_bounds__(512)
postproc_kernel(const float* __restrict__ logits,
                const float* __restrict__ pboxes,
                const float* __restrict__ vecs,
                const int*   __restrict__ tsz,
                float* __restrict__ out)
{
    __shared__ __align__(16) unsigned char sm[SMEM_BYTES];
    unsigned short* Ctb = (unsigned short*)(sm + CTB_OFF);
    unsigned short* A1  = (unsigned short*)(sm + A1_OFF);
    unsigned short* Ab  = (unsigned short*)(sm + ABUF_OFF);
    float*          red = (float*)(sm + RED_OFF);

    const int br  = blockIdx.x;
    const int tid = threadIdx.x;

    // ---------- Part A: scores / labels / boxes (wave 0 only; exact fp32 path) ----------
    if (tid < 64) {
        const float* lrow = logits + (size_t)br * NCLS;
        float p = 1.0f / (1.0f + expf(-lrow[tid]));
        int   bi = tid;
        if (tid < NCLS - 64) {
            float p2 = 1.0f / (1.0f + expf(-lrow[tid + 64]));
            if (p2 > p) { p = p2; bi = tid + 64; }    // tie -> keep lower index
        }
        #pragma unroll
        for (int off = 32; off > 0; off >>= 1) {
            float po = __shfl_xor(p, off, 64);
            int   io = __shfl_xor(bi, off, 64);
            if (po > p || (po == p && io < bi)) { p = po; bi = io; }
        }
        if (tid == 0) {
            out[br] = p;
            out[NROWS + br] = (float)bi;
            const int b = br / 300;
            const float W = (float)tsz[2 * b + 1];
            const float H = (float)tsz[2 * b + 0];
            const float4 bx = *(const float4*)(pboxes + (size_t)br * 4);
            float4 o;
            o.x = (bx.x - 0.5f * bx.z) * W;
            o.y = (bx.y - 0.5f * bx.w) * H;
            o.z = (bx.x + 0.5f * bx.z) * W;
            o.w = (bx.y + 0.5f * bx.w) * H;
            *(float4*)(out + 2 * NROWS + (size_t)br * 4) = o;
        }
    }

    // ---------- Single staging phase: Ctb build (f32 cos), A1 complement-zero, scatter ----------
    {
        const float s0 = 0.08838834764831845f;           // sqrt(1/128)
        for (int idx = tid; idx < 128 * 32; idx += 512) {
            const int i = idx >> 5, k = idx & 31;
            float v;
            if (k == 0)       v = s0;
            else if (k < 23) {
                const int t = ((2 * i + 1) * k) & 511;   // exact integer phase, period 512
                v = 0.125f * __cosf((float)t * 0.012271846303085129f);  // pi/256
            } else            v = 0.0f;
            Ctb[i * STR + k] = f2bf(v);
        }
        // also zero the pad cols k in [32,40)
        for (int idx = tid; idx < 128 * 4; idx += 512) { // 4 u16x2 = 8 ushorts
            const int i = idx >> 2, q = idx & 3;
            ((unsigned int*)(Ctb + i * STR + 32))[q] = 0u;
        }
    }
    // A1: zero only the complement of the zigzag-scattered set (disjoint writes)
    for (int idx = tid; idx < 32 * STR; idx += 512) {
        const int vv = idx / STR, u = idx - vv * STR;
        const int s = u + vv;
        if (s > 22 || (s == 22 && u < 20)) A1[idx] = 0;
    }
    if (tid < NKEEP) {
        const int k = tid;
        int s = 0;
        while ((s + 1) * (s + 2) / 2 <= k) ++s;          // zigzag diagonal, s <= 22
        const int r = k - s * (s + 1) / 2;
        const int u  = (s & 1) ? r : (s - r);
        const int vv = (s & 1) ? (s - r) : r;
        A1[vv * STR + u] = f2bf(vecs[(size_t)br * NKEEP + k]);
    }
    __syncthreads();

    const int w  = tid >> 6;                             // wave id 0..7 (uniform)
    const int ml = tid & 15;
    const int kq = (tid & 63) >> 4;                      // quad 0..3

    // ---------- Stage 1 MFMA: D1[v][i] = sum_u A1[v][u] * C[u][i] -> Ab[i][v] (bf16) ----------
    {
        const f32x4 cz = {0.0f, 0.0f, 0.0f, 0.0f};
        #pragma unroll
        for (int p = 0; p < 2; ++p) {
            const int idx = 2 * w + p;                   // 16 tiles: tr in {0,1}, tc in 0..7
            const int tr = idx >> 3, tc = idx & 7;
            bf16x8 a1 = *(const bf16x8*)(A1  + (tr * 16 + ml) * STR + kq * 8);
            bf16x8 b1 = *(const bf16x8*)(Ctb + (tc * 16 + ml) * STR + kq * 8);
            f32x4 d1 = __builtin_amdgcn_mfma_f32_16x16x32_bf16(a1, b1, cz, 0, 0, 0);
            #pragma unroll
            for (int r = 0; r < 4; ++r)
                Ab[(tc * 16 + ml) * STR + tr * 16 + kq * 4 + r] = f2bf(d1[r]);
        }
    }
    __syncthreads();

    // ---------- Stage 2 MFMA: re[i][j] = sum_v Ab[i][v] * C[v][j] ----------
    f32x4 acc[8];
    {
        const f32x4 cz = {0.0f, 0.0f, 0.0f, 0.0f};
        bf16x8 a2 = *(const bf16x8*)(Ab + (w * 16 + ml) * STR + kq * 8);
        #pragma unroll
        for (int s = 0; s < 8; ++s) {
            bf16x8 b2 = *(const bf16x8*)(Ctb + (s * 16 + ml) * STR + kq * 8);
            acc[s] = __builtin_amdgcn_mfma_f32_16x16x32_bf16(a2, b2, cz, 0, 0, 0);
        }
    }

    // ---------- min/max reduce -> threshold ----------
    float mn = acc[0][0], mx = acc[0][0];
    #pragma unroll
    for (int s = 0; s < 8; ++s)
        #pragma unroll
        for (int r = 0; r < 4; ++r) {
            mn = fminf(mn, acc[s][r]);
            mx = fmaxf(mx, acc[s][r]);
        }
    #pragma unroll
    for (int off = 32; off > 0; off >>= 1) {
        mn = fminf(mn, __shfl_xor(mn, off, 64));
        mx = fmaxf(mx, __shfl_xor(mx, off, 64));
    }
    if ((tid & 63) == 0) { red[w] = mn; red[8 + w] = mx; }
    __syncthreads();
    float gmn = red[0], gmx = red[8];
    #pragma unroll
    for (int k = 1; k < 8; ++k) {
        gmn = fminf(gmn, red[k]);
        gmx = fmaxf(gmx, red[8 + k]);
    }
    const float thr = (gmx + gmn) * 0.5f;

    // ---------- binarize + store (C-layout: row = w*16 + kq*4 + r, col = s*16 + ml) ----------
    float* omask = out + 6 * NROWS + (size_t)br * (L * L);
    #pragma unroll
    for (int s = 0; s < 8; ++s)
        #pragma unroll
        for (int r = 0; r < 4; ++r)
            omask[(size_t)(w * 16 + kq * 4 + r) * L + s * 16 + ml] =
                acc[s][r] > thr ? 1.0f : 0.0f;
}

extern "C" void kernel_launch(void* const* d_in, const int* in_sizes, int n_in,
                              void* d_out, int out_size, void* d_ws, size_t ws_size,
                              hipStream_t stream)
{
    const float* logits = (const float*)d_in[0];
    const float* pboxes = (const float*)d_in[1];
    const float* vecs   = (const float*)d_in[2];
    const int*   tsz    = (const int*)d_in[3];
    float* out = (float*)d_out;
    (void)d_ws; (void)ws_size; (void)in_sizes; (void)n_in; (void)out_size;

    postproc_kernel<<<dim3(NROWS), dim3(512), 0, stream>>>(logits, pboxes, vecs, tsz, out);
}

// Round 10
// 171.768 us; speedup vs baseline: 1.3068x; 1.0036x over previous
//
#include <hip/hip_runtime.h>
#include <math.h>

#define NROWS 2400
#define NCLS  91
#define L     128
#define KSUB  23
#define NKEEP 256
#define STR   40    // ushort row stride: 80B -> 16B-aligned, 2-way banks (free)

typedef short  bf16x8 __attribute__((ext_vector_type(8)));   // 8 bf16 = 4 VGPRs
typedef float  f32x4  __attribute__((ext_vector_type(4)));

// LDS byte layout (phase 1: frag buffers; phase 2 overlay: Lbuf):
// [0,     10240)  Ctb[128][STR] ushort : Ctb[i][k] = bf16(C[k][i]); k in [23,40) zero
// [10240, 12800)  A1 [32][STR]  ushort : A1[v][u] = bf16(coef[u][v]); zero elsewhere
// [12800, 23040)  Ab [128][STR] ushort : Ab[i][v] = bf16(M1t[v][i])
// overlay after threshold barrier:
// [0,     33792)  Lbuf[64][132] float  (stride 132 words: +4 mod 32 banks/row)
// [33792, 33856)  red[16] float
#define CTB_OFF  0
#define A1_OFF   10240
#define ABUF_OFF 12800
#define RED_OFF  33792
#define LBUF_STRIDE 132
#define SMEM_BYTES 33856

__device__ __forceinline__ unsigned short f2bf(float f) {
    unsigned int u = __float_as_uint(f);
    unsigned int r = u + 0x7fffu + ((u >> 16) & 1u);   // round-to-nearest-even
    return (unsigned short)(r >> 16);
}

__global__ void __launch_bounds__(512)
postproc_kernel(const float* __restrict__ logits,
                const float* __restrict__ pboxes,
                const float* __restrict__ vecs,
                const int*   __restrict__ tsz,
                float* __restrict__ out)
{
    __shared__ __align__(16) unsigned char sm[SMEM_BYTES];
    unsigned short* Ctb = (unsigned short*)(sm + CTB_OFF);
    unsigned short* A1  = (unsigned short*)(sm + A1_OFF);
    unsigned short* Ab  = (unsigned short*)(sm + ABUF_OFF);
    float*          red = (float*)(sm + RED_OFF);
    float*          Lbuf = (float*)sm;

    const int br  = blockIdx.x;
    const int tid = threadIdx.x;

    // ---------- Part A: scores / labels / boxes (wave 0 only; exact fp32 path) ----------
    if (tid < 64) {
        const float* lrow = logits + (size_t)br * NCLS;
        float p = 1.0f / (1.0f + expf(-lrow[tid]));
        int   bi = tid;
        if (tid < NCLS - 64) {
            float p2 = 1.0f / (1.0f + expf(-lrow[tid + 64]));
            if (p2 > p) { p = p2; bi = tid + 64; }    // tie -> keep lower index
        }
        #pragma unroll
        for (int off = 32; off > 0; off >>= 1) {
            float po = __shfl_xor(p, off, 64);
            int   io = __shfl_xor(bi, off, 64);
            if (po > p || (po == p && io < bi)) { p = po; bi = io; }
        }
        if (tid == 0) {
            out[br] = p;
            out[NROWS + br] = (float)bi;
            const int b = br / 300;
            const float W = (float)tsz[2 * b + 1];
            const float H = (float)tsz[2 * b + 0];
            const float4 bx = *(const float4*)(pboxes + (size_t)br * 4);
            float4 o;
            o.x = (bx.x - 0.5f * bx.z) * W;
            o.y = (bx.y - 0.5f * bx.w) * H;
            o.z = (bx.x + 0.5f * bx.z) * W;
            o.w = (bx.y + 0.5f * bx.w) * H;
            *(float4*)(out + 2 * NROWS + (size_t)br * 4) = o;
        }
    }

    // ---------- Single staging phase: Ctb build (f32 cos), A1 complement-zero, scatter ----------
    {
        const float s0 = 0.08838834764831845f;           // sqrt(1/128)
        for (int idx = tid; idx < 128 * 32; idx += 512) {
            const int i = idx >> 5, k = idx & 31;
            float v;
            if (k == 0)       v = s0;
            else if (k < 23) {
                const int t = ((2 * i + 1) * k) & 511;   // exact integer phase, period 512
                v = 0.125f * __cosf((float)t * 0.012271846303085129f);  // pi/256
            } else            v = 0.0f;
            Ctb[i * STR + k] = f2bf(v);
        }
        for (int idx = tid; idx < 128 * 4; idx += 512) { // zero pad cols k in [32,40)
            const int i = idx >> 2, q = idx & 3;
            ((unsigned int*)(Ctb + i * STR + 32))[q] = 0u;
        }
    }
    for (int idx = tid; idx < 32 * STR; idx += 512) {    // A1 complement-zero
        const int vv = idx / STR, u = idx - vv * STR;
        const int s = u + vv;
        if (s > 22 || (s == 22 && u < 20)) A1[idx] = 0;
    }
    if (tid < NKEEP) {
        const int k = tid;
        int s = 0;
        while ((s + 1) * (s + 2) / 2 <= k) ++s;          // zigzag diagonal, s <= 22
        const int r = k - s * (s + 1) / 2;
        const int u  = (s & 1) ? r : (s - r);
        const int vv = (s & 1) ? (s - r) : r;
        A1[vv * STR + u] = f2bf(vecs[(size_t)br * NKEEP + k]);
    }
    __syncthreads();

    const int w  = tid >> 6;                             // wave id 0..7 (uniform)
    const int ml = tid & 15;
    const int kq = (tid & 63) >> 4;                      // quad 0..3

    // ---------- Stage 1 MFMA: D1[v][i] = sum_u A1[v][u] * C[u][i] -> Ab[i][v] (bf16) ----------
    {
        const f32x4 cz = {0.0f, 0.0f, 0.0f, 0.0f};
        #pragma unroll
        for (int p = 0; p < 2; ++p) {
            const int idx = 2 * w + p;                   // 16 tiles: tr in {0,1}, tc in 0..7
            const int tr = idx >> 3, tc = idx & 7;
            bf16x8 a1 = *(const bf16x8*)(A1  + (tr * 16 + ml) * STR + kq * 8);
            bf16x8 b1 = *(const bf16x8*)(Ctb + (tc * 16 + ml) * STR + kq * 8);
            f32x4 d1 = __builtin_amdgcn_mfma_f32_16x16x32_bf16(a1, b1, cz, 0, 0, 0);
            #pragma unroll
            for (int r = 0; r < 4; ++r)
                Ab[(tc * 16 + ml) * STR + tr * 16 + kq * 4 + r] = f2bf(d1[r]);
        }
    }
    __syncthreads();

    // ---------- Stage 2 MFMA: re[i][j] = sum_v Ab[i][v] * C[v][j] ----------
    f32x4 acc[8];
    {
        const f32x4 cz = {0.0f, 0.0f, 0.0f, 0.0f};
        bf16x8 a2 = *(const bf16x8*)(Ab + (w * 16 + ml) * STR + kq * 8);
        #pragma unroll
        for (int s = 0; s < 8; ++s) {
            bf16x8 b2 = *(const bf16x8*)(Ctb + (s * 16 + ml) * STR + kq * 8);
            acc[s] = __builtin_amdgcn_mfma_f32_16x16x32_bf16(a2, b2, cz, 0, 0, 0);
        }
    }

    // ---------- min/max reduce -> threshold ----------
    float mn = acc[0][0], mx = acc[0][0];
    #pragma unroll
    for (int s = 0; s < 8; ++s)
        #pragma unroll
        for (int r = 0; r < 4; ++r) {
            mn = fminf(mn, acc[s][r]);
            mx = fmaxf(mx, acc[s][r]);
        }
    #pragma unroll
    for (int off = 32; off > 0; off >>= 1) {
        mn = fminf(mn, __shfl_xor(mn, off, 64));
        mx = fmaxf(mx, __shfl_xor(mx, off, 64));
    }
    if ((tid & 63) == 0) { red[w] = mn; red[8 + w] = mx; }
    __syncthreads();                                     // frag buffers dead after this
    float gmn = red[0], gmx = red[8];
    #pragma unroll
    for (int k = 1; k < 8; ++k) {
        gmn = fminf(gmn, red[k]);
        gmx = fmaxf(gmx, red[8 + k]);
    }
    const float thr = (gmx + gmn) * 0.5f;

    // ---------- binarize -> Lbuf (64-row chunks) -> perfectly coalesced float4 stores ----------
    float* omask = out + 6 * NROWS + (size_t)br * (L * L);
    #pragma unroll
    for (int c = 0; c < 2; ++c) {
        if ((w >> 2) == c) {                             // waves owning rows [64c, 64c+64)
            const int lr0 = (w - c * 4) * 16 + kq * 4;   // local row base in chunk
            #pragma unroll
            for (int s = 0; s < 8; ++s)
                #pragma unroll
                for (int r = 0; r < 4; ++r)
                    Lbuf[(lr0 + r) * LBUF_STRIDE + s * 16 + ml] =
                        acc[s][r] > thr ? 1.0f : 0.0f;
        }
        __syncthreads();
        float* obase = omask + c * 8192;                 // 64 rows * 128 cols
        #pragma unroll
        for (int q = 0; q < 4; ++q) {
            const int flat4 = q * 512 + tid;             // 2048 float4 per chunk
            const int row = flat4 >> 5, c4 = flat4 & 31;
            *(float4*)(obase + flat4 * 4) =
                *(const float4*)(Lbuf + row * LBUF_STRIDE + c4 * 4);
        }
        if (c == 0) __syncthreads();                     // chunk-1 writes wait for reads
    }
}

extern "C" void kernel_launch(void* const* d_in, const int* in_sizes, int n_in,
                              void* d_out, int out_size, void* d_ws, size_t ws_size,
                              hipStream_t stream)
{
    const float* logits = (const float*)d_in[0];
    const float* pboxes = (const float*)d_in[1];
    const float* vecs   = (const float*)d_in[2];
    const int*   tsz    = (const int*)d_in[3];
    float* out = (float*)d_out;
    (void)d_ws; (void)ws_size; (void)in_sizes; (void)n_in; (void)out_size;

    postproc_kernel<<<dim3(NROWS), dim3(512), 0, stream>>>(logits, pboxes, vecs, tsz, out);
}